// Round 1
// baseline (2092.357 us; speedup 1.0000x reference)
//
#include <hip/hip_runtime.h>
#include <math.h>

#define NL 4
#define Dm 512
#define Hh 8
#define HD 64
#define FFD 1024
#define Bb 8
#define Ss 480
#define TPT 15
#define CAPF 6.0f
#define NEGF -1e30f
#define ROWS (Bb*Ss)   // 3840

// ---------------- LayerNorm: one block (256 thr) per row, D=512 ----------------
__global__ __launch_bounds__(256) void ln_kernel(const float* __restrict__ x,
                                                 const float* __restrict__ g,
                                                 const float* __restrict__ b,
                                                 float* __restrict__ out) {
    int row = blockIdx.x;
    const float* xr = x + (size_t)row * Dm;
    int tid = threadIdx.x;
    int wid = tid >> 6, lane = tid & 63;
    float v0 = xr[tid], v1 = xr[tid + 256];

    __shared__ float red[8];
    float s = v0 + v1;
    for (int off = 32; off; off >>= 1) s += __shfl_down(s, off);
    if (lane == 0) red[wid] = s;
    __syncthreads();
    if (tid == 0) red[0] = (red[0] + red[1] + red[2] + red[3]) * (1.0f / Dm);
    __syncthreads();
    float mean = red[0];

    float d0 = v0 - mean, d1 = v1 - mean;
    float ss = d0 * d0 + d1 * d1;
    for (int off = 32; off; off >>= 1) ss += __shfl_down(ss, off);
    if (lane == 0) red[4 + wid] = ss;
    __syncthreads();
    if (tid == 0) red[4] = (red[4] + red[5] + red[6] + red[7]) * (1.0f / Dm);
    __syncthreads();
    float rstd = rsqrtf(red[4] + 1e-5f);

    out[(size_t)row * Dm + tid]       = d0 * rstd * g[tid]       + b[tid];
    out[(size_t)row * Dm + tid + 256] = d1 * rstd * g[tid + 256] + b[tid + 256];
}

// ------------- fp32 tiled GEMM 64x64x16, 256 threads, 4x4 per thread -----------
// C[M,N] = act(A[M,K] @ B[K,N] + bias) (+ res).  ACT: 0 none, 1 exact GELU.
template <int ACT, int RES>
__global__ __launch_bounds__(256) void gemm_kernel(const float* __restrict__ A,
                                                   const float* __restrict__ B,
                                                   const float* __restrict__ bias,
                                                   const float* __restrict__ res,
                                                   float* __restrict__ C,
                                                   int M, int N, int K) {
    __shared__ float As[64][17];
    __shared__ float Bs[16][65];
    int bm = blockIdx.y * 64, bn = blockIdx.x * 64;
    int tid = threadIdx.x;
    int tx = tid & 15, ty = tid >> 4;
    float acc[4][4] = {};

    for (int k0 = 0; k0 < K; k0 += 16) {
        {   // A tile: 64 rows x 16 k
            int r = tid >> 2, c = (tid & 3) * 4;
            float4 v = *(const float4*)(A + (size_t)(bm + r) * K + k0 + c);
            As[r][c] = v.x; As[r][c + 1] = v.y; As[r][c + 2] = v.z; As[r][c + 3] = v.w;
        }
        {   // B tile: 16 k x 64 cols
            int r = tid >> 4, c = (tid & 15) * 4;
            float4 v = *(const float4*)(B + (size_t)(k0 + r) * N + bn + c);
            Bs[r][c] = v.x; Bs[r][c + 1] = v.y; Bs[r][c + 2] = v.z; Bs[r][c + 3] = v.w;
        }
        __syncthreads();
#pragma unroll
        for (int kk = 0; kk < 16; kk++) {
            float a[4], bb[4];
#pragma unroll
            for (int i = 0; i < 4; i++) a[i] = As[ty * 4 + i][kk];
#pragma unroll
            for (int j = 0; j < 4; j++) bb[j] = Bs[kk][tx * 4 + j];
#pragma unroll
            for (int i = 0; i < 4; i++)
#pragma unroll
                for (int j = 0; j < 4; j++) acc[i][j] += a[i] * bb[j];
        }
        __syncthreads();
    }

#pragma unroll
    for (int i = 0; i < 4; i++) {
        int m = bm + ty * 4 + i;
#pragma unroll
        for (int j = 0; j < 4; j++) {
            int n = bn + tx * 4 + j;
            float v = acc[i][j] + bias[n];
            if (ACT == 1) v = 0.5f * v * (1.0f + erff(v * 0.70710678118f));
            if (RES) v += res[(size_t)m * N + n];
            C[(size_t)m * N + n] = v;
        }
    }
}

// ---------------- Attention: 1 wave per query, mask-aware sparse ---------------
// qkv packed [B,S,3*D]: q at col h*64+d, k at 512+h*64+d, v at 1024+h*64+d.
__global__ __launch_bounds__(256) void attn_kernel(const float* __restrict__ qkv,
                                                   const int* __restrict__ ids,
                                                   const int* __restrict__ npf_p,
                                                   float* __restrict__ out) {
    int w = threadIdx.x >> 6, lane = threadIdx.x & 63;
    int gq = blockIdx.x * 4 + w;          // b*H*S + h*S + q
    int q = gq % Ss;
    int bh = gq / Ss;
    int h = bh % Hh;
    int b = bh / Hh;
    int npf = npf_p[0];

    __shared__ float qs[4][64];
    __shared__ float ps[4][Ss];

    const float* qptr = qkv + ((size_t)(b * Ss + q)) * (3 * Dm) + h * HD;
    qs[w][lane] = qptr[lane];
    __syncthreads();

    int qt = q / TPT;
    int qid = ids[b * Ss + q];

    float s[8];
    float m = -INFINITY;
#pragma unroll
    for (int t = 0; t < 8; t++) {
        int k = lane + t * 64;
        s[t] = NEGF;
        if (k < Ss) {
            int kt = k / TPT, ki = k % TPT;
            bool allowed = (ids[b * Ss + k] == qid) &&
                           ((kt == qt) || ((ki == 0) && (kt < qt) && (qt - kt <= npf)));
            if (allowed) {
                const float* kptr = qkv + ((size_t)(b * Ss + k)) * (3 * Dm) + Dm + h * HD;
                float dot = 0.0f;
                for (int d = 0; d < HD; d++) dot += qs[w][d] * kptr[d];
                dot *= 0.125f;                       // 1/sqrt(64)
                s[t] = CAPF * tanhf(dot * (1.0f / CAPF));
            }
        }
        m = fmaxf(m, s[t]);
    }
    for (int off = 32; off; off >>= 1) m = fmaxf(m, __shfl_xor(m, off));

    float l = 0.0f;
#pragma unroll
    for (int t = 0; t < 8; t++) {
        int k = lane + t * 64;
        if (k < Ss) {
            float p = expf(s[t] - m);   // masked: exp(-1e30 - m) == 0
            ps[w][k] = p;
            l += p;
        }
    }
    for (int off = 32; off; off >>= 1) l += __shfl_xor(l, off);
    __syncthreads();

    float inv = 1.0f / l;
    float o = 0.0f;
    for (int k = 0; k < Ss; k++) {
        float p = ps[w][k];             // uniform across wave (broadcast)
        if (p != 0.0f) {
            o += p * qkv[((size_t)(b * Ss + k)) * (3 * Dm) + 2 * Dm + h * HD + lane];
        }
    }
    out[((size_t)(b * Ss + q)) * Dm + h * HD + lane] = o * inv;
}

extern "C" void kernel_launch(void* const* d_in, const int* in_sizes, int n_in,
                              void* d_out, int out_size, void* d_ws, size_t ws_size,
                              hipStream_t stream) {
    const float* x    = (const float*)d_in[0];
    const int*   ids  = (const int*)d_in[1];
    const int*   npf  = (const int*)d_in[2];
    const float* Wqkv = (const float*)d_in[3];
    const float* bqkv = (const float*)d_in[4];
    const float* Wo   = (const float*)d_in[5];
    const float* bo   = (const float*)d_in[6];
    const float* g1   = (const float*)d_in[7];
    const float* b1   = (const float*)d_in[8];
    const float* g2   = (const float*)d_in[9];
    const float* b2   = (const float*)d_in[10];
    const float* W1   = (const float*)d_in[11];
    const float* bf1  = (const float*)d_in[12];
    const float* W2   = (const float*)d_in[13];
    const float* bf2  = (const float*)d_in[14];
    float* out = (float*)d_out;

    float* h     = (float*)d_ws;                 // [ROWS, 512]
    float* qkvb  = h + (size_t)ROWS * Dm;        // [ROWS, 1536]
    float* attnb = qkvb + (size_t)ROWS * 3 * Dm; // [ROWS, 512]
    float* fb    = attnb + (size_t)ROWS * Dm;    // [ROWS, 1024]

    for (int l = 0; l < NL; l++) {
        const float* xin = (l == 0) ? x : out;
        ln_kernel<<<ROWS, 256, 0, stream>>>(xin, g1 + l * Dm, b1 + l * Dm, h);
        gemm_kernel<0, 0><<<dim3(24, 60), 256, 0, stream>>>(
            h, Wqkv + (size_t)l * Dm * 3 * Dm, bqkv + l * 3 * Dm, nullptr, qkvb,
            ROWS, 3 * Dm, Dm);
        attn_kernel<<<ROWS * Hh / 4, 256, 0, stream>>>(qkvb, ids, npf, attnb);
        gemm_kernel<0, 1><<<dim3(8, 60), 256, 0, stream>>>(
            attnb, Wo + (size_t)l * Dm * Dm, bo + l * Dm, xin, out,
            ROWS, Dm, Dm);
        ln_kernel<<<ROWS, 256, 0, stream>>>(out, g2 + l * Dm, b2 + l * Dm, h);
        gemm_kernel<1, 0><<<dim3(16, 60), 256, 0, stream>>>(
            h, W1 + (size_t)l * Dm * FFD, bf1 + l * FFD, nullptr, fb,
            ROWS, FFD, Dm);
        gemm_kernel<0, 1><<<dim3(8, 60), 256, 0, stream>>>(
            fb, W2 + (size_t)l * FFD * Dm, bf2 + l * Dm, out, out,
            ROWS, Dm, FFD);
    }
}

// Round 2
// 527.087 us; speedup vs baseline: 3.9697x; 3.9697x over previous
//
#include <hip/hip_runtime.h>
#include <hip/hip_bf16.h>
#include <math.h>

#define NL 4
#define Dm 512
#define Hh 8
#define HD 64
#define FFD 1024
#define Bb 8
#define Ss 480
#define TPT 15
#define CAPF 6.0f
#define ROWS (Bb*Ss)   // 3840

typedef __attribute__((ext_vector_type(8))) short short8v;
typedef __attribute__((ext_vector_type(4))) float f32x4;

__device__ __forceinline__ float bf2f(short u) {
    unsigned x = ((unsigned)(unsigned short)u) << 16;
    return __builtin_bit_cast(float, x);
}

// ---------------- LayerNorm: one block (256 thr) per row, D=512; bf16 out -------
__global__ __launch_bounds__(256) void ln_kernel(const float* __restrict__ x,
                                                 const float* __restrict__ g,
                                                 const float* __restrict__ b,
                                                 __hip_bfloat16* __restrict__ out) {
    int row = blockIdx.x;
    const float* xr = x + (size_t)row * Dm;
    int tid = threadIdx.x;
    int wid = tid >> 6, lane = tid & 63;
    float v0 = xr[tid], v1 = xr[tid + 256];

    __shared__ float red[8];
    float s = v0 + v1;
    for (int off = 32; off; off >>= 1) s += __shfl_down(s, off);
    if (lane == 0) red[wid] = s;
    __syncthreads();
    if (tid == 0) red[0] = (red[0] + red[1] + red[2] + red[3]) * (1.0f / Dm);
    __syncthreads();
    float mean = red[0];

    float d0 = v0 - mean, d1 = v1 - mean;
    float ss = d0 * d0 + d1 * d1;
    for (int off = 32; off; off >>= 1) ss += __shfl_down(ss, off);
    if (lane == 0) red[4 + wid] = ss;
    __syncthreads();
    if (tid == 0) red[4] = (red[4] + red[5] + red[6] + red[7]) * (1.0f / Dm);
    __syncthreads();
    float rstd = rsqrtf(red[4] + 1e-5f);

    out[(size_t)row * Dm + tid]       = __float2bfloat16(d0 * rstd * g[tid]       + b[tid]);
    out[(size_t)row * Dm + tid + 256] = __float2bfloat16(d1 * rstd * g[tid + 256] + b[tid + 256]);
}

// --------- weight transpose+convert: [K][N] fp32 -> [N][K] bf16, per layer z ----
__global__ __launch_bounds__(256) void conv_t_kernel(const float* __restrict__ in,
                                                     __hip_bfloat16* __restrict__ out,
                                                     int K, int N) {
    const float* inz = in + (size_t)blockIdx.z * K * N;
    __hip_bfloat16* outz = out + (size_t)blockIdx.z * K * N;
    __shared__ float t[32][33];
    int n0 = blockIdx.x * 32, k0 = blockIdx.y * 32;
    int tx = threadIdx.x & 31, ty = threadIdx.x >> 5;   // 32 x 8
#pragma unroll
    for (int r = 0; r < 4; r++)
        t[ty * 4 + r][tx] = inz[(size_t)(k0 + ty * 4 + r) * N + n0 + tx];
    __syncthreads();
#pragma unroll
    for (int r = 0; r < 4; r++)
        outz[(size_t)(n0 + ty * 4 + r) * K + k0 + tx] = __float2bfloat16(t[tx][ty * 4 + r]);
}

// ---------------- bf16 MFMA GEMM: 128x128 tile, BK=64, 4 waves ------------------
// C = act(A[M,K] @ Bt[N,K]^T + bias) (+ res).  XOR-swizzled LDS, ds_read_b128.
template <int ACT, int RES, int OUTBF>
__global__ __launch_bounds__(256) void gemm_bf16(const __hip_bfloat16* __restrict__ A,
                                                 const __hip_bfloat16* __restrict__ Bt,
                                                 const float* __restrict__ bias,
                                                 const float* __restrict__ res,
                                                 void* __restrict__ C,
                                                 int M, int N, int K) {
    __shared__ __align__(16) short As[128 * 64];
    __shared__ __align__(16) short Bs[128 * 64];
    const int bm = blockIdx.y * 128, bn = blockIdx.x * 128;
    const int tid = threadIdx.x;
    const int w = tid >> 6, lane = tid & 63;
    const int wm = (w >> 1) * 64, wn = (w & 1) * 64;
    const int l16 = lane & 15, lq = lane >> 4;
    const short* Ag = (const short*)A;
    const short* Bg = (const short*)Bt;

    f32x4 acc[4][4] = {};

    for (int k0 = 0; k0 < K; k0 += 64) {
        // stage: each thread 4 x 16B for A and for B, swizzled chunk = (k/8)^(row&7)
#pragma unroll
        for (int c = 0; c < 4; c++) {
            int e = (c * 256 + tid) * 8;
            int row = e >> 6, kk = e & 63;
            int chs = ((kk >> 3) ^ (row & 7)) * 8;
            *(short8v*)(&As[row * 64 + chs]) =
                *(const short8v*)(&Ag[(size_t)(bm + row) * K + k0 + kk]);
            *(short8v*)(&Bs[row * 64 + chs]) =
                *(const short8v*)(&Bg[(size_t)(bn + row) * K + k0 + kk]);
        }
        __syncthreads();
#pragma unroll
        for (int kc = 0; kc < 2; kc++) {
            short8v af[4], bf[4];
#pragma unroll
            for (int i = 0; i < 4; i++) {
                int row = wm + i * 16 + l16;                 // A row in tile
                int ch = ((kc * 4 + lq) ^ (row & 7)) * 8;
                af[i] = *(const short8v*)(&As[row * 64 + ch]);
                int col = wn + i * 16 + l16;                 // B col (= Bs row)
                int ch2 = ((kc * 4 + lq) ^ (col & 7)) * 8;
                bf[i] = *(const short8v*)(&Bs[col * 64 + ch2]);
            }
#pragma unroll
            for (int i = 0; i < 4; i++)
#pragma unroll
                for (int j = 0; j < 4; j++)
                    acc[i][j] = __builtin_amdgcn_mfma_f32_16x16x32_bf16(
                        af[i], bf[j], acc[i][j], 0, 0, 0);
        }
        __syncthreads();
    }

#pragma unroll
    for (int i = 0; i < 4; i++) {
#pragma unroll
        for (int j = 0; j < 4; j++) {
#pragma unroll
            for (int r = 0; r < 4; r++) {
                int mrow = bm + wm + i * 16 + lq * 4 + r;
                int ncol = bn + wn + j * 16 + l16;
                float v = acc[i][j][r] + bias[ncol];
                if (ACT == 1) v = 0.5f * v * (1.0f + erff(v * 0.70710678118f));
                if (RES) v += res[(size_t)mrow * N + ncol];
                if (OUTBF) ((__hip_bfloat16*)C)[(size_t)mrow * N + ncol] = __float2bfloat16(v);
                else       ((float*)C)[(size_t)mrow * N + ncol] = v;
            }
        }
    }
}

// ------------- Attention: candidate-list sparse, 1 wave per (b,q,h) -------------
// qkv bf16 [B*S][1536]: q at h*64+d, k at 512+h*64+d, v at 1024+h*64+d.
__global__ __launch_bounds__(256) void attn_sparse(const __hip_bfloat16* __restrict__ qkv,
                                                   const int* __restrict__ ids,
                                                   const int* __restrict__ npf_p,
                                                   __hip_bfloat16* __restrict__ outb) {
    __shared__ float qs[4][64];
    __shared__ float ps[4][24];
    __shared__ int   kid[4][24];
    int w = threadIdx.x >> 6, lane = threadIdx.x & 63;
    int g = blockIdx.x * 4 + w;            // ((b*S+q)*H + h)
    int h = g & 7;
    int bq = g >> 3;                       // b*S + q
    int q = bq % Ss;
    int b = bq / Ss;
    int npf = npf_p[0];
    int qt = q / TPT;
    int qid = ids[bq];
    const short* qkvs = (const short*)qkv;

    qs[w][lane] = bf2f(qkvs[(size_t)bq * 1536 + h * 64 + lane]);
    __syncthreads();

    float s = -INFINITY;
    int kk = -1;
    if (lane < 23) {
        int k; bool ok;
        if (lane < 15) { k = qt * TPT + lane; ok = true; }
        else { int dt = lane - 14; int kt = qt - dt; k = kt * TPT; ok = (kt >= 0) && (dt <= npf); }
        if (ok && ids[b * Ss + k] == qid) {
            const short8v* kr = (const short8v*)&qkvs[(size_t)(b * Ss + k) * 1536 + 512 + h * 64];
            float dot = 0.0f;
#pragma unroll
            for (int c = 0; c < 8; c++) {
                short8v kv = kr[c];
#pragma unroll
                for (int e = 0; e < 8; e++) dot += qs[w][c * 8 + e] * bf2f(kv[e]);
            }
            s = CAPF * tanhf(dot * (0.125f / CAPF));
            kk = k;
        }
    }
    float m = s;
    for (int off = 32; off; off >>= 1) m = fmaxf(m, __shfl_xor(m, off));
    float p = (kk >= 0) ? expf(s - m) : 0.0f;
    float l = p;
    for (int off = 32; off; off >>= 1) l += __shfl_xor(l, off);
    if (lane < 24) { ps[w][lane] = (lane < 23) ? p : 0.0f; kid[w][lane] = (lane < 23) ? kk : -1; }
    __syncthreads();

    float inv = 1.0f / l;
    float o = 0.0f;
    for (int j = 0; j < 23; j++) {
        float pj = ps[w][j];
        if (pj > 0.0f) {
            int k = kid[w][j];
            o += pj * bf2f(qkvs[(size_t)(b * Ss + k) * 1536 + 1024 + h * 64 + lane]);
        }
    }
    outb[(size_t)bq * Dm + h * 64 + lane] = __float2bfloat16(o * inv);
}

extern "C" void kernel_launch(void* const* d_in, const int* in_sizes, int n_in,
                              void* d_out, int out_size, void* d_ws, size_t ws_size,
                              hipStream_t stream) {
    const float* x    = (const float*)d_in[0];
    const int*   ids  = (const int*)d_in[1];
    const int*   npf  = (const int*)d_in[2];
    const float* Wqkv = (const float*)d_in[3];
    const float* bqkv = (const float*)d_in[4];
    const float* Wo   = (const float*)d_in[5];
    const float* bo   = (const float*)d_in[6];
    const float* g1   = (const float*)d_in[7];
    const float* b1   = (const float*)d_in[8];
    const float* g2   = (const float*)d_in[9];
    const float* b2   = (const float*)d_in[10];
    const float* W1   = (const float*)d_in[11];
    const float* bf1  = (const float*)d_in[12];
    const float* W2   = (const float*)d_in[13];
    const float* bf2  = (const float*)d_in[14];
    float* out = (float*)d_out;

    char* p = (char*)d_ws;
    __hip_bfloat16* hb    = (__hip_bfloat16*)p;                 p += (size_t)ROWS * Dm * 2;
    __hip_bfloat16* qkvb  = (__hip_bfloat16*)p;                 p += (size_t)ROWS * 3 * Dm * 2;
    __hip_bfloat16* attnb = (__hip_bfloat16*)p;                 p += (size_t)ROWS * Dm * 2;
    __hip_bfloat16* fb    = (__hip_bfloat16*)p;                 p += (size_t)ROWS * FFD * 2;
    __hip_bfloat16* Wqkv_t= (__hip_bfloat16*)p;                 p += (size_t)NL * Dm * 3 * Dm * 2;
    __hip_bfloat16* Wo_t  = (__hip_bfloat16*)p;                 p += (size_t)NL * Dm * Dm * 2;
    __hip_bfloat16* W1_t  = (__hip_bfloat16*)p;                 p += (size_t)NL * Dm * FFD * 2;
    __hip_bfloat16* W2_t  = (__hip_bfloat16*)p;                 p += (size_t)NL * FFD * Dm * 2;

    // one-time (per launch) weight transpose + bf16 convert
    conv_t_kernel<<<dim3(3 * Dm / 32, Dm / 32, NL), 256, 0, stream>>>(Wqkv, Wqkv_t, Dm, 3 * Dm);
    conv_t_kernel<<<dim3(Dm / 32, Dm / 32, NL),     256, 0, stream>>>(Wo,   Wo_t,   Dm, Dm);
    conv_t_kernel<<<dim3(FFD / 32, Dm / 32, NL),    256, 0, stream>>>(W1,   W1_t,   Dm, FFD);
    conv_t_kernel<<<dim3(Dm / 32, FFD / 32, NL),    256, 0, stream>>>(W2,   W2_t,   FFD, Dm);

    for (int l = 0; l < NL; l++) {
        const float* xin = (l == 0) ? x : out;
        ln_kernel<<<ROWS, 256, 0, stream>>>(xin, g1 + l * Dm, b1 + l * Dm, hb);
        gemm_bf16<0, 0, 1><<<dim3(12, 30), 256, 0, stream>>>(
            hb, Wqkv_t + (size_t)l * Dm * 3 * Dm, bqkv + l * 3 * Dm, nullptr, qkvb,
            ROWS, 3 * Dm, Dm);
        attn_sparse<<<ROWS * Hh / 4, 256, 0, stream>>>(qkvb, ids, npf, attnb);
        gemm_bf16<0, 1, 0><<<dim3(4, 30), 256, 0, stream>>>(
            attnb, Wo_t + (size_t)l * Dm * Dm, bo + l * Dm, xin, out,
            ROWS, Dm, Dm);
        ln_kernel<<<ROWS, 256, 0, stream>>>(out, g2 + l * Dm, b2 + l * Dm, hb);
        gemm_bf16<1, 0, 1><<<dim3(8, 30), 256, 0, stream>>>(
            hb, W1_t + (size_t)l * Dm * FFD, bf1 + l * FFD, nullptr, fb,
            ROWS, FFD, Dm);
        gemm_bf16<0, 1, 0><<<dim3(4, 30), 256, 0, stream>>>(
            fb, W2_t + (size_t)l * FFD * Dm, bf2 + l * Dm, out, out,
            ROWS, Dm, FFD);
    }
}

// Round 3
// 346.853 us; speedup vs baseline: 6.0324x; 1.5196x over previous
//
#include <hip/hip_runtime.h>
#include <hip/hip_bf16.h>
#include <hip/hip_fp16.h>
#include <math.h>

#define NL 4
#define Dm 512
#define Hh 8
#define FFD 1024
#define Bb 8
#define Ss 480
#define TPT 15
#define ROWS (Bb*Ss)   // 3840

typedef __attribute__((ext_vector_type(8))) short short8v;
typedef __attribute__((ext_vector_type(4))) float f32x4;
typedef __attribute__((ext_vector_type(2))) _Float16 half2v;
typedef __attribute__((ext_vector_type(8))) _Float16 half8v;

#if __has_builtin(__builtin_amdgcn_fdot2)
#define FDOT2(a, b, c) __builtin_amdgcn_fdot2(a, b, c, false)
#else
#define FDOT2(a, b, c) ((c) + (float)(a)[0] * (float)(b)[0] + (float)(a)[1] * (float)(b)[1])
#endif

// global -> LDS direct (16B per lane). lbase must be wave-uniform; HW dest = lbase + lane*16.
__device__ __forceinline__ void gld_lds16(const void* g, void* lbase, int lane) {
#if __has_builtin(__builtin_amdgcn_global_load_lds)
    __builtin_amdgcn_global_load_lds((const __attribute__((address_space(1))) void*)g,
                                     (__attribute__((address_space(3))) void*)lbase, 16, 0, 0);
#else
    *(short8v*)((char*)lbase + lane * 16) = *(const short8v*)g;
#endif
}

// ---------------- LayerNorm: one block (256 thr) per row, D=512; bf16 out -------
__global__ __launch_bounds__(256) void ln_kernel(const float* __restrict__ x,
                                                 const float* __restrict__ g,
                                                 const float* __restrict__ b,
                                                 __hip_bfloat16* __restrict__ out) {
    int row = blockIdx.x;
    const float* xr = x + (size_t)row * Dm;
    int tid = threadIdx.x;
    int wid = tid >> 6, lane = tid & 63;
    float v0 = xr[tid], v1 = xr[tid + 256];

    __shared__ float red[8];
    float s = v0 + v1;
    for (int off = 32; off; off >>= 1) s += __shfl_down(s, off);
    if (lane == 0) red[wid] = s;
    __syncthreads();
    if (tid == 0) red[0] = (red[0] + red[1] + red[2] + red[3]) * (1.0f / Dm);
    __syncthreads();
    float mean = red[0];

    float d0 = v0 - mean, d1 = v1 - mean;
    float ss = d0 * d0 + d1 * d1;
    for (int off = 32; off; off >>= 1) ss += __shfl_down(ss, off);
    if (lane == 0) red[4 + wid] = ss;
    __syncthreads();
    if (tid == 0) red[4] = (red[4] + red[5] + red[6] + red[7]) * (1.0f / Dm);
    __syncthreads();
    float rstd = rsqrtf(red[4] + 1e-5f);

    out[(size_t)row * Dm + tid]       = __float2bfloat16(d0 * rstd * g[tid]       + b[tid]);
    out[(size_t)row * Dm + tid + 256] = __float2bfloat16(d1 * rstd * g[tid + 256] + b[tid + 256]);
}

// --------- weight transpose+convert: [K][N] fp32 -> [N][K] bf16, per layer z ----
__global__ __launch_bounds__(256) void conv_t_kernel(const float* __restrict__ in,
                                                     __hip_bfloat16* __restrict__ out,
                                                     int K, int N) {
    const float* inz = in + (size_t)blockIdx.z * K * N;
    __hip_bfloat16* outz = out + (size_t)blockIdx.z * K * N;
    __shared__ float t[32][33];
    int n0 = blockIdx.x * 32, k0 = blockIdx.y * 32;
    int tx = threadIdx.x & 31, ty = threadIdx.x >> 5;   // 32 x 8
#pragma unroll
    for (int r = 0; r < 4; r++)
        t[ty * 4 + r][tx] = inz[(size_t)(k0 + ty * 4 + r) * N + n0 + tx];
    __syncthreads();
#pragma unroll
    for (int r = 0; r < 4; r++)
        outz[(size_t)(n0 + ty * 4 + r) * K + k0 + tx] = __float2bfloat16(t[tx][ty * 4 + r]);
}

// ------------- bf16 MFMA GEMM: 64x64 tile, BK=64, 4 waves (each 32x32) ----------
// C = act(A[M,K] @ Bt[N,K]^T + bias) (+res). global_load_lds staging with
// pre-swizzled global source; XOR-swizzled ds_read_b128 fragments (0 conflicts).
// OUTMODE: 0 = f32, 1 = bf16, 2 = f16.
template <int ACT, int RES, int OUTMODE>
__global__ __launch_bounds__(256) void gemm_mfma(const __hip_bfloat16* __restrict__ A,
                                                 const __hip_bfloat16* __restrict__ Bt,
                                                 const float* __restrict__ bias,
                                                 const float* __restrict__ res,
                                                 void* __restrict__ C,
                                                 int M, int N, int K) {
    __shared__ __align__(16) short As[64 * 64];
    __shared__ __align__(16) short Bs[64 * 64];
    const int bm = blockIdx.y * 64, bn = blockIdx.x * 64;
    const int tid = threadIdx.x;
    const int w = tid >> 6, lane = tid & 63;
    const int wm = (w >> 1) * 32, wn = (w & 1) * 32;
    const int l16 = lane & 15, lq = lane >> 4;
    const short* Ag = (const short*)A;
    const short* Bg = (const short*)Bt;

    f32x4 acc[2][2] = {};

    for (int k0 = 0; k0 < K; k0 += 64) {
#pragma unroll
        for (int r = 0; r < 2; ++r) {
            int row = r * 32 + w * 8 + (lane >> 3);        // tile row this lane stages
            int csrc = (lane & 7) ^ (row & 7);             // pre-swizzled source chunk
            void* la = &As[(size_t)(r * 4096 + w * 1024) / 2];  // byte base /2 -> short idx
            void* lb = &Bs[(size_t)(r * 4096 + w * 1024) / 2];
            gld_lds16(Ag + (size_t)(bm + row) * K + k0 + csrc * 8, la, lane);
            gld_lds16(Bg + (size_t)(bn + row) * K + k0 + csrc * 8, lb, lane);
        }
        __syncthreads();
#pragma unroll
        for (int kc = 0; kc < 2; ++kc) {
            short8v af[2], bf[2];
#pragma unroll
            for (int i = 0; i < 2; i++) {
                int row = wm + i * 16 + l16;
                int ch = (kc * 4 + lq) ^ (row & 7);
                af[i] = *(const short8v*)(&As[row * 64 + ch * 8]);
                int col = wn + i * 16 + l16;
                int ch2 = (kc * 4 + lq) ^ (col & 7);
                bf[i] = *(const short8v*)(&Bs[col * 64 + ch2 * 8]);
            }
#pragma unroll
            for (int i = 0; i < 2; i++)
#pragma unroll
                for (int j = 0; j < 2; j++)
                    acc[i][j] = __builtin_amdgcn_mfma_f32_16x16x32_bf16(
                        af[i], bf[j], acc[i][j], 0, 0, 0);
        }
        __syncthreads();
    }

#pragma unroll
    for (int i = 0; i < 2; i++) {
#pragma unroll
        for (int j = 0; j < 2; j++) {
#pragma unroll
            for (int r = 0; r < 4; r++) {
                int mrow = bm + wm + i * 16 + lq * 4 + r;
                int ncol = bn + wn + j * 16 + l16;
                float v = acc[i][j][r] + bias[ncol];
                if (ACT == 1) v = 0.5f * v * (1.0f + erff(v * 0.70710678118f));
                if (RES) v += res[(size_t)mrow * N + ncol];
                if (OUTMODE == 0)      ((float*)C)[(size_t)mrow * N + ncol] = v;
                else if (OUTMODE == 1) ((__hip_bfloat16*)C)[(size_t)mrow * N + ncol] = __float2bfloat16(v);
                else                   ((__half*)C)[(size_t)mrow * N + ncol] = __float2half(v);
            }
        }
    }
}

// ------------- Attention: 1 wave per (b,q), all 8 heads, f16 fdot2 --------------
// qkv f16 [B*S][1536]: q at d, k at 512+d, v at 1024+d (d = h*64 + dim).
// Score phase: lane = h*8 + cpart, candidates {cpart, cpart+8, cpart+16}.
// PV phase:    lane = h*8 + dg, output dims dg*8..dg*8+7.
__global__ __launch_bounds__(256) void attn_sparse(const _Float16* __restrict__ qkv,
                                                   const int* __restrict__ ids,
                                                   const int* __restrict__ npf_p,
                                                   __hip_bfloat16* __restrict__ outb) {
    __shared__ _Float16 qs[4][512];
    __shared__ float ps[4][Hh][24];
    int w = threadIdx.x >> 6, lane = threadIdx.x & 63;
    int bq = blockIdx.x * 4 + w;           // b*S + q
    int q = bq % Ss, b = bq / Ss;
    int npf = npf_p[0];
    int qt = q / TPT;
    int qid = ids[bq];

    // stage this query's q-row (512 f16 = 1KB): one 16B chunk per lane
    *(half8v*)&qs[w][lane * 8] = *(const half8v*)&qkv[(size_t)bq * 1536 + lane * 8];
    __syncthreads();

    int h = lane >> 3, cp = lane & 7;

    // q slice for head h into regs (broadcast LDS reads within 8-lane group)
    half2v qreg[32];
#pragma unroll
    for (int i = 0; i < 32; i++) qreg[i] = *(const half2v*)&qs[w][h * 64 + i * 2];

    float s[3];
#pragma unroll
    for (int i = 0; i < 3; i++) {
        int c = cp + i * 8;
        float sv = -INFINITY;
        if (c < 23) {
            bool ok; int k;
            if (c < 15) { k = qt * TPT + c; ok = true; }
            else { int dt = c - 14; int kt = qt - dt; k = kt * TPT; ok = (kt >= 0) && (dt <= npf); }
            if (ok && ids[b * Ss + k] == qid) {
                const half8v* kr = (const half8v*)&qkv[(size_t)(b * Ss + k) * 1536 + 512 + h * 64];
                float dot = 0.0f;
#pragma unroll
                for (int cch = 0; cch < 8; cch++) {
                    half8v kv = kr[cch];
#pragma unroll
                    for (int e = 0; e < 4; e++) {
                        half2v kk = { kv[e * 2], kv[e * 2 + 1] };
                        dot = FDOT2(qreg[cch * 4 + e], kk, dot);
                    }
                }
                sv = 6.0f * tanhf(dot * (0.125f / 6.0f));   // 1/sqrt(64), soft cap 6
            }
        }
        s[i] = sv;
    }

    float m = fmaxf(fmaxf(s[0], s[1]), s[2]);
    for (int off = 1; off < 8; off <<= 1) m = fmaxf(m, __shfl_xor(m, off));
    float p0 = expf(s[0] - m), p1 = expf(s[1] - m), p2 = expf(s[2] - m);
    float l = p0 + p1 + p2;
    for (int off = 1; off < 8; off <<= 1) l += __shfl_xor(l, off);
    float inv = 1.0f / l;
    if (cp < 8)       ps[w][h][cp]      = p0 * inv;
    if (cp + 8 < 23)  ps[w][h][cp + 8]  = p1 * inv;
    if (cp + 16 < 23) ps[w][h][cp + 16] = p2 * inv;
    __syncthreads();

    // PV: lane = (h, dg); 8 output dims per lane
    int dg = lane & 7;
    float o[8] = {};
    for (int c = 0; c < 23; c++) {
        float p = ps[w][h][c];
        if (p != 0.0f) {
            int k = (c < 15) ? (qt * TPT + c) : ((qt - (c - 14)) * TPT);
            half8v vv = *(const half8v*)&qkv[(size_t)(b * Ss + k) * 1536 + 1024 + h * 64 + dg * 8];
#pragma unroll
            for (int e = 0; e < 8; e++) o[e] += p * (float)vv[e];
        }
    }
    short8v pack;
#pragma unroll
    for (int e = 0; e < 8; e++) {
        __hip_bfloat16 t = __float2bfloat16(o[e]);
        pack[e] = __builtin_bit_cast(short, t);
    }
    *(short8v*)&outb[(size_t)bq * Dm + h * 64 + dg * 8] = pack;
}

extern "C" void kernel_launch(void* const* d_in, const int* in_sizes, int n_in,
                              void* d_out, int out_size, void* d_ws, size_t ws_size,
                              hipStream_t stream) {
    const float* x    = (const float*)d_in[0];
    const int*   ids  = (const int*)d_in[1];
    const int*   npf  = (const int*)d_in[2];
    const float* Wqkv = (const float*)d_in[3];
    const float* bqkv = (const float*)d_in[4];
    const float* Wo   = (const float*)d_in[5];
    const float* bo   = (const float*)d_in[6];
    const float* g1   = (const float*)d_in[7];
    const float* b1   = (const float*)d_in[8];
    const float* g2   = (const float*)d_in[9];
    const float* b2   = (const float*)d_in[10];
    const float* W1   = (const float*)d_in[11];
    const float* bf1  = (const float*)d_in[12];
    const float* W2   = (const float*)d_in[13];
    const float* bf2  = (const float*)d_in[14];
    float* out = (float*)d_out;

    char* p = (char*)d_ws;
    __hip_bfloat16* hb    = (__hip_bfloat16*)p;   p += (size_t)ROWS * Dm * 2;
    _Float16*       qkvb  = (_Float16*)p;         p += (size_t)ROWS * 3 * Dm * 2;
    __hip_bfloat16* attnb = (__hip_bfloat16*)p;   p += (size_t)ROWS * Dm * 2;
    __hip_bfloat16* fb    = (__hip_bfloat16*)p;   p += (size_t)ROWS * FFD * 2;
    __hip_bfloat16* Wqkv_t= (__hip_bfloat16*)p;   p += (size_t)NL * Dm * 3 * Dm * 2;
    __hip_bfloat16* Wo_t  = (__hip_bfloat16*)p;   p += (size_t)NL * Dm * Dm * 2;
    __hip_bfloat16* W1_t  = (__hip_bfloat16*)p;   p += (size_t)NL * Dm * FFD * 2;
    __hip_bfloat16* W2_t  = (__hip_bfloat16*)p;   p += (size_t)NL * FFD * Dm * 2;

    conv_t_kernel<<<dim3(3 * Dm / 32, Dm / 32, NL), 256, 0, stream>>>(Wqkv, Wqkv_t, Dm, 3 * Dm);
    conv_t_kernel<<<dim3(Dm / 32, Dm / 32, NL),     256, 0, stream>>>(Wo,   Wo_t,   Dm, Dm);
    conv_t_kernel<<<dim3(FFD / 32, Dm / 32, NL),    256, 0, stream>>>(W1,   W1_t,   Dm, FFD);
    conv_t_kernel<<<dim3(Dm / 32, FFD / 32, NL),    256, 0, stream>>>(W2,   W2_t,   FFD, Dm);

    for (int l = 0; l < NL; l++) {
        const float* xin = (l == 0) ? x : out;
        ln_kernel<<<ROWS, 256, 0, stream>>>(xin, g1 + l * Dm, b1 + l * Dm, hb);
        gemm_mfma<0, 0, 2><<<dim3(24, 60), 256, 0, stream>>>(
            hb, Wqkv_t + (size_t)l * Dm * 3 * Dm, bqkv + l * 3 * Dm, nullptr, qkvb,
            ROWS, 3 * Dm, Dm);
        attn_sparse<<<ROWS / 4, 256, 0, stream>>>(qkvb, ids, npf, attnb);
        gemm_mfma<0, 1, 0><<<dim3(8, 60), 256, 0, stream>>>(
            attnb, Wo_t + (size_t)l * Dm * Dm, bo + l * Dm, xin, out,
            ROWS, Dm, Dm);
        ln_kernel<<<ROWS, 256, 0, stream>>>(out, g2 + l * Dm, b2 + l * Dm, hb);
        gemm_mfma<1, 0, 1><<<dim3(16, 60), 256, 0, stream>>>(
            hb, W1_t + (size_t)l * Dm * FFD, bf1 + l * FFD, nullptr, fb,
            ROWS, FFD, Dm);
        gemm_mfma<0, 1, 0><<<dim3(8, 60), 256, 0, stream>>>(
            fb, W2_t + (size_t)l * FFD * Dm, bf2 + l * Dm, out, out,
            ROWS, Dm, FFD);
    }
}

// Round 4
// 322.572 us; speedup vs baseline: 6.4865x; 1.0753x over previous
//
#include <hip/hip_runtime.h>
#include <hip/hip_bf16.h>
#include <hip/hip_fp16.h>
#include <math.h>

#define NL 4
#define Dm 512
#define Hh 8
#define FFD 1024
#define Bb 8
#define Ss 480
#define TPT 15
#define ROWS (Bb*Ss)   // 3840

typedef __attribute__((ext_vector_type(8))) short short8v;
typedef __attribute__((ext_vector_type(4))) float f32x4;
typedef __attribute__((ext_vector_type(2))) _Float16 half2v;
typedef __attribute__((ext_vector_type(8))) _Float16 half8v;

#if __has_builtin(__builtin_amdgcn_fdot2)
#define FDOT2(a, b, c) __builtin_amdgcn_fdot2(a, b, c, false)
#else
#define FDOT2(a, b, c) ((c) + (float)(a)[0] * (float)(b)[0] + (float)(a)[1] * (float)(b)[1])
#endif

// global -> LDS direct (16B per lane). lbase must be wave-uniform; HW dest = lbase + lane*16.
__device__ __forceinline__ void gld_lds16(const void* g, void* lbase, int lane) {
#if __has_builtin(__builtin_amdgcn_global_load_lds)
    __builtin_amdgcn_global_load_lds((const __attribute__((address_space(1))) void*)g,
                                     (__attribute__((address_space(3))) void*)lbase, 16, 0, 0);
#else
    *(short8v*)((char*)lbase + lane * 16) = *(const short8v*)g;
#endif
}

// ---------------- LayerNorm: one WAVE per row, D=512; bf16 out ------------------
__global__ __launch_bounds__(256) void ln_kernel(const float* __restrict__ x,
                                                 const float* __restrict__ g,
                                                 const float* __restrict__ b,
                                                 __hip_bfloat16* __restrict__ out) {
    int w = threadIdx.x >> 6, lane = threadIdx.x & 63;
    int row = blockIdx.x * 4 + w;
    const float* xr = x + (size_t)row * Dm + lane * 8;
    float4 v0 = *(const float4*)xr;
    float4 v1 = *(const float4*)(xr + 4);
    float v[8] = { v0.x, v0.y, v0.z, v0.w, v1.x, v1.y, v1.z, v1.w };

    float s = 0.0f;
#pragma unroll
    for (int e = 0; e < 8; e++) s += v[e];
#pragma unroll
    for (int off = 1; off < 64; off <<= 1) s += __shfl_xor(s, off);
    float mean = s * (1.0f / Dm);

    float ss = 0.0f;
#pragma unroll
    for (int e = 0; e < 8; e++) { v[e] -= mean; ss += v[e] * v[e]; }
#pragma unroll
    for (int off = 1; off < 64; off <<= 1) ss += __shfl_xor(ss, off);
    float rstd = rsqrtf(ss * (1.0f / Dm) + 1e-5f);

    const float* gp = g + lane * 8;
    const float* bp = b + lane * 8;
    float4 g0 = *(const float4*)gp, g1 = *(const float4*)(gp + 4);
    float4 b0 = *(const float4*)bp, b1 = *(const float4*)(bp + 4);
    float gg[8] = { g0.x, g0.y, g0.z, g0.w, g1.x, g1.y, g1.z, g1.w };
    float bb[8] = { b0.x, b0.y, b0.z, b0.w, b1.x, b1.y, b1.z, b1.w };
    short8v pack;
#pragma unroll
    for (int e = 0; e < 8; e++) {
        __hip_bfloat16 t = __float2bfloat16(v[e] * rstd * gg[e] + bb[e]);
        pack[e] = __builtin_bit_cast(short, t);
    }
    *(short8v*)&out[(size_t)row * Dm + lane * 8] = pack;
}

// -------- merged weight transpose+convert: all 4 weight types, all layers -------
// [K][N] fp32 -> [N][K] bf16.  blockIdx.z = type*4 + layer.
__global__ __launch_bounds__(256) void conv_all(const float* __restrict__ Wqkv,
                                                const float* __restrict__ Wo,
                                                const float* __restrict__ W1,
                                                const float* __restrict__ W2,
                                                __hip_bfloat16* __restrict__ oq,
                                                __hip_bfloat16* __restrict__ oo,
                                                __hip_bfloat16* __restrict__ o1,
                                                __hip_bfloat16* __restrict__ o2) {
    int type = blockIdx.z >> 2, l = blockIdx.z & 3;
    int K, N; const float* src; __hip_bfloat16* dst;
    if (type == 0)      { K = 512;  N = 1536; src = Wqkv; dst = oq; }
    else if (type == 1) { K = 512;  N = 512;  src = Wo;   dst = oo; }
    else if (type == 2) { K = 512;  N = 1024; src = W1;   dst = o1; }
    else                { K = 1024; N = 512;  src = W2;   dst = o2; }
    int n0 = blockIdx.x * 32, k0 = blockIdx.y * 32;
    if (n0 >= N || k0 >= K) return;         // block-uniform exit
    src += (size_t)l * K * N;
    dst += (size_t)l * K * N;

    __shared__ float t[32][33];
    int tx = threadIdx.x & 31, ty = threadIdx.x >> 5;   // 32 x 8
#pragma unroll
    for (int r = 0; r < 4; r++)
        t[ty * 4 + r][tx] = src[(size_t)(k0 + ty * 4 + r) * N + n0 + tx];
    __syncthreads();
#pragma unroll
    for (int r = 0; r < 4; r++)
        dst[(size_t)(n0 + ty * 4 + r) * K + k0 + tx] = __float2bfloat16(t[tx][ty * 4 + r]);
}

// ---- bf16 MFMA GEMM: BMx64 tile, BK=64, 4 waves, 2-phase double-buffered -------
// C = act(A[M,K] @ Bt[N,K]^T + bias) (+res). global_load_lds with pre-swizzled
// source; XOR-swizzled ds_read_b128. OUTMODE: 0 = f32, 1 = bf16, 2 = f16.
template <int BM, int ACT, int RES, int OUTMODE>
__global__ __launch_bounds__(256) void gemm_mfma(const __hip_bfloat16* __restrict__ A,
                                                 const __hip_bfloat16* __restrict__ Bt,
                                                 const float* __restrict__ bias,
                                                 const float* __restrict__ res,
                                                 void* __restrict__ C,
                                                 int M, int N, int K) {
    constexpr int MF = BM / 32;          // m-frags per wave (128->4, 64->2)
    constexpr int AC = BM / 32;          // A staging chunks per thread
    __shared__ __align__(16) short As[2][BM * 64];
    __shared__ __align__(16) short Bs[2][64 * 64];
    const int bm = blockIdx.y * BM, bn = blockIdx.x * 64;
    const int tid = threadIdx.x;
    const int w = tid >> 6, lane = tid & 63;
    const int wm = (w >> 1) * (BM / 2), wn = (w & 1) * 32;
    const int l16 = lane & 15, lq = lane >> 4;
    const short* Ag = (const short*)A;
    const short* Bg = (const short*)Bt;
    const int nt = K >> 6;

    f32x4 acc[MF][2] = {};

    auto stage = [&](int t, int buf) {
        int k0 = t << 6;
#pragma unroll
        for (int c = 0; c < AC; ++c) {
            int e = c * 256 + tid;                 // 16B chunk id
            int row = e >> 3;
            int csrc = (e & 7) ^ (row & 7);        // pre-swizzled source chunk
            gld_lds16(Ag + (size_t)(bm + row) * K + k0 + csrc * 8,
                      &As[buf][(c * 256 + w * 64) * 8], lane);
        }
#pragma unroll
        for (int c = 0; c < 2; ++c) {
            int e = c * 256 + tid;
            int row = e >> 3;
            int csrc = (e & 7) ^ (row & 7);
            gld_lds16(Bg + (size_t)(bn + row) * K + k0 + csrc * 8,
                      &Bs[buf][(c * 256 + w * 64) * 8], lane);
        }
    };

    stage(0, 0);
    __syncthreads();                 // drains vmcnt(0) before first reads
    int cur = 0;
    for (int t = 0; t < nt; ++t) {
        if (t + 1 < nt) stage(t + 1, cur ^ 1);   // prefetch next tile (in flight)
#pragma unroll
        for (int kc = 0; kc < 2; ++kc) {
            short8v af[MF], bf[2];
#pragma unroll
            for (int i = 0; i < MF; i++) {
                int row = wm + i * 16 + l16;
                int ch = (kc * 4 + lq) ^ (row & 7);
                af[i] = *(const short8v*)(&As[cur][row * 64 + ch * 8]);
            }
#pragma unroll
            for (int j = 0; j < 2; j++) {
                int col = wn + j * 16 + l16;
                int ch2 = (kc * 4 + lq) ^ (col & 7);
                bf[j] = *(const short8v*)(&Bs[cur][col * 64 + ch2 * 8]);
            }
#pragma unroll
            for (int i = 0; i < MF; i++)
#pragma unroll
                for (int j = 0; j < 2; j++)
                    acc[i][j] = __builtin_amdgcn_mfma_f32_16x16x32_bf16(
                        af[i], bf[j], acc[i][j], 0, 0, 0);
        }
        __syncthreads();             // drains vmcnt(0): next tile ready, reads done
        cur ^= 1;
    }

#pragma unroll
    for (int i = 0; i < MF; i++) {
#pragma unroll
        for (int j = 0; j < 2; j++) {
#pragma unroll
            for (int r = 0; r < 4; r++) {
                int mrow = bm + wm + i * 16 + lq * 4 + r;
                int ncol = bn + wn + j * 16 + l16;
                float v = acc[i][j][r] + bias[ncol];
                if (ACT == 1) v = 0.5f * v * (1.0f + erff(v * 0.70710678118f));
                if (RES) v += res[(size_t)mrow * N + ncol];
                if (OUTMODE == 0)      ((float*)C)[(size_t)mrow * N + ncol] = v;
                else if (OUTMODE == 1) ((__hip_bfloat16*)C)[(size_t)mrow * N + ncol] = __float2bfloat16(v);
                else                   ((__half*)C)[(size_t)mrow * N + ncol] = __float2half(v);
            }
        }
    }
}

// ------------- Attention: 1 wave per (b,q), all 8 heads, f16 fdot2 --------------
// qkv f16 [B*S][1536]: q at d, k at 512+d, v at 1024+d (d = h*64 + dim).
__global__ __launch_bounds__(256) void attn_sparse(const _Float16* __restrict__ qkv,
                                                   const int* __restrict__ ids,
                                                   const int* __restrict__ npf_p,
                                                   __hip_bfloat16* __restrict__ outb) {
    __shared__ _Float16 qs[4][512];
    __shared__ float ps[4][Hh][24];
    int w = threadIdx.x >> 6, lane = threadIdx.x & 63;
    int bq = blockIdx.x * 4 + w;           // b*S + q
    int q = bq % Ss, b = bq / Ss;
    int npf = npf_p[0];
    int qt = q / TPT;
    int qid = ids[bq];

    *(half8v*)&qs[w][lane * 8] = *(const half8v*)&qkv[(size_t)bq * 1536 + lane * 8];
    __syncthreads();

    int h = lane >> 3, cp = lane & 7;

    half2v qreg[32];
#pragma unroll
    for (int i = 0; i < 32; i++) qreg[i] = *(const half2v*)&qs[w][h * 64 + i * 2];

    float s[3];
#pragma unroll
    for (int i = 0; i < 3; i++) {
        int c = cp + i * 8;
        float sv = -INFINITY;
        if (c < 23) {
            bool ok; int k;
            if (c < 15) { k = qt * TPT + c; ok = true; }
            else { int dt = c - 14; int kt = qt - dt; k = kt * TPT; ok = (kt >= 0) && (dt <= npf); }
            if (ok && ids[b * Ss + k] == qid) {
                const half8v* kr = (const half8v*)&qkv[(size_t)(b * Ss + k) * 1536 + 512 + h * 64];
                float dot = 0.0f;
#pragma unroll
                for (int cch = 0; cch < 8; cch++) {
                    half8v kv = kr[cch];
#pragma unroll
                    for (int e = 0; e < 4; e++) {
                        half2v kk = { kv[e * 2], kv[e * 2 + 1] };
                        dot = FDOT2(qreg[cch * 4 + e], kk, dot);
                    }
                }
                sv = 6.0f * tanhf(dot * (0.125f / 6.0f));
            }
        }
        s[i] = sv;
    }

    float m = fmaxf(fmaxf(s[0], s[1]), s[2]);
    for (int off = 1; off < 8; off <<= 1) m = fmaxf(m, __shfl_xor(m, off));
    float p0 = expf(s[0] - m), p1 = expf(s[1] - m), p2 = expf(s[2] - m);
    float l = p0 + p1 + p2;
    for (int off = 1; off < 8; off <<= 1) l += __shfl_xor(l, off);
    float inv = 1.0f / l;
    if (cp < 8)       ps[w][h][cp]      = p0 * inv;
    if (cp + 8 < 23)  ps[w][h][cp + 8]  = p1 * inv;
    if (cp + 16 < 23) ps[w][h][cp + 16] = p2 * inv;
    __syncthreads();

    int dg = lane & 7;
    float o[8] = {};
    for (int c = 0; c < 23; c++) {
        float p = ps[w][h][c];
        if (p != 0.0f) {
            int k = (c < 15) ? (qt * TPT + c) : ((qt - (c - 14)) * TPT);
            half8v vv = *(const half8v*)&qkv[(size_t)(b * Ss + k) * 1536 + 1024 + h * 64 + dg * 8];
#pragma unroll
            for (int e = 0; e < 8; e++) o[e] += p * (float)vv[e];
        }
    }
    short8v pack;
#pragma unroll
    for (int e = 0; e < 8; e++) {
        __hip_bfloat16 t = __float2bfloat16(o[e]);
        pack[e] = __builtin_bit_cast(short, t);
    }
    *(short8v*)&outb[(size_t)bq * Dm + h * 64 + dg * 8] = pack;
}

extern "C" void kernel_launch(void* const* d_in, const int* in_sizes, int n_in,
                              void* d_out, int out_size, void* d_ws, size_t ws_size,
                              hipStream_t stream) {
    const float* x    = (const float*)d_in[0];
    const int*   ids  = (const int*)d_in[1];
    const int*   npf  = (const int*)d_in[2];
    const float* Wqkv = (const float*)d_in[3];
    const float* bqkv = (const float*)d_in[4];
    const float* Wo   = (const float*)d_in[5];
    const float* bo   = (const float*)d_in[6];
    const float* g1   = (const float*)d_in[7];
    const float* b1   = (const float*)d_in[8];
    const float* g2   = (const float*)d_in[9];
    const float* b2   = (const float*)d_in[10];
    const float* W1   = (const float*)d_in[11];
    const float* bf1  = (const float*)d_in[12];
    const float* W2   = (const float*)d_in[13];
    const float* bf2  = (const float*)d_in[14];
    float* out = (float*)d_out;

    char* p = (char*)d_ws;
    __hip_bfloat16* hb    = (__hip_bfloat16*)p;   p += (size_t)ROWS * Dm * 2;
    _Float16*       qkvb  = (_Float16*)p;         p += (size_t)ROWS * 3 * Dm * 2;
    __hip_bfloat16* attnb = (__hip_bfloat16*)p;   p += (size_t)ROWS * Dm * 2;
    __hip_bfloat16* fb    = (__hip_bfloat16*)p;   p += (size_t)ROWS * FFD * 2;
    __hip_bfloat16* Wqkv_t= (__hip_bfloat16*)p;   p += (size_t)NL * Dm * 3 * Dm * 2;
    __hip_bfloat16* Wo_t  = (__hip_bfloat16*)p;   p += (size_t)NL * Dm * Dm * 2;
    __hip_bfloat16* W1_t  = (__hip_bfloat16*)p;   p += (size_t)NL * Dm * FFD * 2;
    __hip_bfloat16* W2_t  = (__hip_bfloat16*)p;   p += (size_t)NL * FFD * Dm * 2;

    conv_all<<<dim3(48, 32, 16), 256, 0, stream>>>(Wqkv, Wo, W1, W2,
                                                   Wqkv_t, Wo_t, W1_t, W2_t);

    for (int l = 0; l < NL; l++) {
        const float* xin = (l == 0) ? x : out;
        ln_kernel<<<ROWS / 4, 256, 0, stream>>>(xin, g1 + l * Dm, b1 + l * Dm, hb);
        gemm_mfma<128, 0, 0, 2><<<dim3(24, 30), 256, 0, stream>>>(
            hb, Wqkv_t + (size_t)l * Dm * 3 * Dm, bqkv + l * 3 * Dm, nullptr, qkvb,
            ROWS, 3 * Dm, Dm);
        attn_sparse<<<ROWS / 4, 256, 0, stream>>>(qkvb, ids, npf, attnb);
        gemm_mfma<64, 0, 1, 0><<<dim3(8, 60), 256, 0, stream>>>(
            attnb, Wo_t + (size_t)l * Dm * Dm, bo + l * Dm, xin, out,
            ROWS, Dm, Dm);
        ln_kernel<<<ROWS / 4, 256, 0, stream>>>(out, g2 + l * Dm, b2 + l * Dm, hb);
        gemm_mfma<128, 1, 0, 1><<<dim3(16, 30), 256, 0, stream>>>(
            hb, W1_t + (size_t)l * Dm * FFD, bf1 + l * FFD, nullptr, fb,
            ROWS, FFD, Dm);
        gemm_mfma<64, 0, 1, 0><<<dim3(8, 60), 256, 0, stream>>>(
            fb, W2_t + (size_t)l * FFD * Dm, bf2 + l * Dm, out, out,
            ROWS, Dm, FFD);
    }
}